// Round 4
// baseline (3533.029 us; speedup 1.0000x reference)
//
#include <hip/hip_runtime.h>
#include <hip/hip_bf16.h>
#include <math.h>

#define B_BATCH 64
#define T_STEPS 256
#define C_COMP  64

// ws layout: floats [0..191] avec, [192..383] cvec; byte 2048+ : scan bf16 weights
#define WSW_BYTE_OFF 2048
#define WHH_OFF 0
#define Q1_OFF 12288
#define K1_OFF 20480
#define Q2_OFF 28672
#define K2_OFF 45056
#define Q3_OFF 61440
#define K3_OFF 77824
// classifier scratch (bytes)
#define C1WB_BYTE 262144
#define C2WB_BYTE 17039360
#define H1B_BYTE  21233664
#define H2B_BYTE  88342528
#define MB16_BYTE 121896960ULL

// output offsets (floats)
#define MAT_OFF  128
#define TL_OFF   67108992
#define PRED_OFF 67141760
#define XC_OFF   68186240

typedef __attribute__((ext_vector_type(8))) short short8;
typedef __attribute__((ext_vector_type(4))) short short4v;
typedef __attribute__((ext_vector_type(4))) float f32x4;
#define MFMA16(a,b,c) __builtin_amdgcn_mfma_f32_16x16x32_bf16(a,b,c,0,0,0)

__device__ __forceinline__ float fsigm(float v) {
    return __builtin_amdgcn_rcpf(1.0f + __expf(-v));
}
__device__ __forceinline__ float ftanh(float v) {
    return 1.0f - 2.0f * __builtin_amdgcn_rcpf(__expf(2.0f * v) + 1.0f);
}
__device__ __forceinline__ short f2bs(float f) {  // RNE f32->bf16 bits
    unsigned u = __float_as_uint(f);
    u += 0x7fffu + ((u >> 16) & 1u);
    return (short)(u >> 16);
}
__device__ __forceinline__ float bf2f(short s) {
    return __uint_as_float(((unsigned)(unsigned short)s) << 16);
}
// XOR swizzle: spreads row-major bf16 tiles across banks for ds_read_b128 (G4 / T2)
__device__ __forceinline__ int swz64(int row, int col) {
    return row * 64 + (col ^ (((row >> 1) & 7) << 3));
}
__device__ __forceinline__ int swz128(int row, int col) {
    return row * 128 + (col ^ (((row >> 1) & 7) << 3));
}
__device__ __forceinline__ void async16(void* lds, const void* g) {
    __builtin_amdgcn_global_load_lds((const __attribute__((address_space(1))) void*)g,
                                     (__attribute__((address_space(3))) void*)lds, 16, 0, 0);
}

// ---------------- precompute rank-1 embedding+input path --------------------------------
__global__ void precompute_kernel(const float* __restrict__ w_ih,
                                  const float* __restrict__ embed_w,
                                  const float* __restrict__ embed_b,
                                  const float* __restrict__ b_ih,
                                  float* __restrict__ avec, float* __restrict__ cvec)
{
    int g = threadIdx.x;
    if (g < 192) {
        float a = 0.f, c = 0.f;
        for (int e = 0; e < 32; ++e) {
            float w = w_ih[g * 32 + e];
            a += w * embed_w[e];
            c += w * embed_b[e];
        }
        avec[g] = a;
        cvec[g] = c + b_ih[g];
    }
}

__global__ void tobf16_kernel(const float* __restrict__ src, short* __restrict__ dst, int n)
{
    int i = blockIdx.x * 256 + threadIdx.x;
    if (i < n) dst[i] = f2bs(src[i]);
}

// one MLP layer slice: this wave computes one 16-col strip s of out[64][128], all 4 m-tiles
template<int KST, int AST, bool RELU>
__device__ __forceinline__ void layerK(const short* __restrict__ A,
                                       const short8* __restrict__ Bf, const float bias,
                                       short* __restrict__ outb,
                                       const int s, const int ln, const int lh)
{
    f32x4 acc[4];
#pragma unroll
    for (int m = 0; m < 4; ++m) acc[m] = (f32x4){bias, bias, bias, bias};
#pragma unroll
    for (int kk = 0; kk < KST; ++kk)
#pragma unroll
        for (int m = 0; m < 4; ++m) {
            const int row = m * 16 + ln;
            short8 a = *(const short8*)&A[row * AST + ((kk * 32 + lh * 8) ^ (((row >> 1) & 7) << 3))];
            acc[m] = MFMA16(a, Bf[kk], acc[m]);
        }
#pragma unroll
    for (int m = 0; m < 4; ++m)
#pragma unroll
        for (int q = 0; q < 4; ++q) {
            const int row = m * 16 + lh * 4 + q;
            float v = acc[m][q];
            if (RELU) v = fmaxf(v, 0.f);
            outb[swz128(row, s * 16 + ln)] = f2bs(v);
        }
}

// ---------------- the scan: one block (16 waves) per batch ------------------------------
__global__ __launch_bounds__(1024) void scan_kernel(
    const float* __restrict__ x, const float* __restrict__ b_hh,
    const float* __restrict__ avec, const float* __restrict__ cvec,
    const short* __restrict__ wsw,
    const float* __restrict__ q1b, const float* __restrict__ q2b, const float* __restrict__ q3b,
    const float* __restrict__ k1b, const float* __restrict__ k2b, const float* __restrict__ k3b,
    const float* __restrict__ gate_bias,
    const float* __restrict__ pred_w, const float* __restrict__ pred_b,
    float* __restrict__ matrices, float* __restrict__ predicted,
    short* __restrict__ mb16, const int use_mb16)
{
    __shared__ __align__(16) float h32[64 * 67];     // fp32 hidden state (odd stride)
    __shared__ __align__(16) short hb [64 * 64];     // h bf16, swizzled
    __shared__ __align__(16) short hbT[64 * 64];     // post-GRU h transposed, swizzled
    __shared__ __align__(16) short qf [64 * 128];    // swizzled
    __shared__ __align__(16) short kf [64 * 128];
    __shared__ __align__(16) char arena[65536];
    __shared__ float avec_s[192], cvec_s[192], bhh_s[192], pw_s[64], xrow[64], red[16];

    short* act1q = (short*)arena;                // [64][128] swz
    short* act1k = (short*)(arena + 16384);
    short* act2q = (short*)(arena + 32768);
    short* act2k = (short*)(arena + 49152);
    float* gates = (float*)arena;                // [64][193] f32 (dead before act1 written)
    float* tf    = (float*)arena;                // [64][67] f32  (dead before next gates)
    short* tb    = (short*)(arena + 17408);      // [64][64] swz

    const int tid = threadIdx.x;
    const int b = blockIdx.x;
    const int w = tid >> 6, lane = tid & 63;
    const int ln = lane & 15, lh = lane >> 4;
    const int path = w >> 3;                     // 0 = q, 1 = k
    const int w8 = w & 7;

    for (int i = tid; i < 64 * 67; i += 1024) h32[i] = 0.f;
    for (int i = tid; i < 64 * 64; i += 1024) { hb[i] = 0; hbT[i] = 0; }
    if (tid < 192) { avec_s[tid] = avec[tid]; cvec_s[tid] = cvec[tid]; bhh_s[tid] = b_hh[tid]; }
    if (tid < 64) pw_s[tid] = pred_w[tid];
    const float pbv = pred_b[0];

    // ---- preload per-wave weight B-fragments (constant across all t) ----
    const short* whh_b = wsw + WHH_OFF;
    const short* l1w = path ? wsw + K1_OFF : wsw + Q1_OFF;
    const short* l2w = path ? wsw + K2_OFF : wsw + Q2_OFF;
    const short* l3w = path ? wsw + K3_OFF : wsw + Q3_OFF;
    const float* l1b = path ? k1b : q1b;
    const float* l2b = path ? k2b : q2b;
    const float* l3b = path ? k3b : q3b;

    short8 Bg[2], B1[2], B2[4], B3[4];
    if (w < 12) {
#pragma unroll
        for (int kk = 0; kk < 2; ++kk)
            Bg[kk] = *(const short8*)&whh_b[(w * 16 + ln) * 64 + kk * 32 + lh * 8];
    }
#pragma unroll
    for (int kk = 0; kk < 2; ++kk)
        B1[kk] = *(const short8*)&l1w[(w8 * 16 + ln) * 64 + kk * 32 + lh * 8];
#pragma unroll
    for (int kk = 0; kk < 4; ++kk) {
        B2[kk] = *(const short8*)&l2w[(w8 * 16 + ln) * 128 + kk * 32 + lh * 8];
        B3[kk] = *(const short8*)&l3w[(w8 * 16 + ln) * 128 + kk * 32 + lh * 8];
    }
    const float b1v = l1b[w8 * 16 + ln];
    const float b2v = l2b[w8 * 16 + ln];
    const float b3v = l3b[w8 * 16 + ln];
    __syncthreads();

    for (int t = 0; t < T_STEPS; ++t) {
        // ===== predictor for step t-1 (post-BTP h) + P1: gates = hb @ w_hh^T =====
        if (t > 0) {
            const int c = tid >> 4, jj = tid & 15;
            float p = 0.f;
#pragma unroll
            for (int u = 0; u < 4; ++u) p = fmaf(h32[c * 67 + jj * 4 + u], pw_s[jj * 4 + u], p);
            p += __shfl_xor(p, 1); p += __shfl_xor(p, 2);
            p += __shfl_xor(p, 4); p += __shfl_xor(p, 8);
            if (jj == 0) predicted[((size_t)b * (T_STEPS - 1) + (t - 1)) * 64 + c] = p + pbv;
        }
        if (w < 12) {
            f32x4 a[4];
#pragma unroll
            for (int m = 0; m < 4; ++m) a[m] = (f32x4){0, 0, 0, 0};
#pragma unroll
            for (int kk = 0; kk < 2; ++kk)
#pragma unroll
                for (int m = 0; m < 4; ++m) {
                    const int row = m * 16 + ln;
                    short8 av = *(const short8*)&hb[swz64(row, kk * 32 + lh * 8)];
                    a[m] = MFMA16(av, Bg[kk], a[m]);
                }
#pragma unroll
            for (int m = 0; m < 4; ++m)
#pragma unroll
                for (int q = 0; q < 4; ++q)
                    gates[(m * 16 + lh * 4 + q) * 193 + w * 16 + ln] = a[m][q];
        }
        if (w == 15) xrow[lane] = x[((size_t)b * T_STEPS + t) * 64 + lane];
        __syncthreads();

        // ===== P2: GRU elementwise -> h32, hb, hbT =====
        {
            const int c = tid >> 4, jseg = (tid & 15) * 4;
            const float xv = xrow[c];
            short4v hv4;
#pragma unroll
            for (int jj = 0; jj < 4; ++jj) {
                const int j = jseg + jj;
                const float ghr = gates[c * 193 + j]       + bhh_s[j];
                const float ghz = gates[c * 193 + 64 + j]  + bhh_s[64 + j];
                const float ghn = gates[c * 193 + 128 + j] + bhh_s[128 + j];
                const float r = fsigm(fmaf(xv, avec_s[j],        cvec_s[j])        + ghr);
                const float z = fsigm(fmaf(xv, avec_s[64 + j],   cvec_s[64 + j])   + ghz);
                const float n = ftanh(fmaf(xv, avec_s[128 + j], cvec_s[128 + j]) + r * ghn);
                const float hold = h32[c * 67 + j];
                const float hn = fmaf(z, hold - n, n);
                h32[c * 67 + j] = hn;
                const short hv = f2bs(hn);
                hv4[jj] = hv;
                hbT[swz64(j, c)] = hv;
            }
            *(short4v*)&hb[c * 64 + (jseg ^ (((c >> 1) & 7) << 3))] = hv4;
        }
        __syncthreads();

        // ===== P3-P5: q / k MLPs (waves 0-7 q, 8-15 k; one 16-col strip each) =====
        layerK<2, 64,  true >(hb, B1, b1v, path ? act1k : act1q, w8, ln, lh);
        __syncthreads();
        layerK<4, 128, true >(path ? act1k : act1q, B2, b2v, path ? act2k : act2q, w8, ln, lh);
        __syncthreads();
        layerK<4, 128, false>(path ? act2k : act2q, B3, b3v, path ? kf : qf, w8, ln, lh);
        __syncthreads();

        // ===== P6: transfer = qf @ kf^T -> tf f32, sumsq -> red =====
        {
            const int m = w >> 2, n = w & 3;
            f32x4 ac = {0, 0, 0, 0};
#pragma unroll
            for (int kk = 0; kk < 4; ++kk) {
                const int rq = m * 16 + ln, rk = n * 16 + ln;
                short8 a  = *(const short8*)&qf[swz128(rq, kk * 32 + lh * 8)];
                short8 bm = *(const short8*)&kf[swz128(rk, kk * 32 + lh * 8)];
                ac = MFMA16(a, bm, ac);
            }
            float ss = 0.f;
#pragma unroll
            for (int q = 0; q < 4; ++q) {
                tf[(m * 16 + lh * 4 + q) * 67 + n * 16 + ln] = ac[q];
                ss = fmaf(ac[q], ac[q], ss);
            }
#pragma unroll
            for (int off = 1; off < 64; off <<= 1) ss += __shfl_xor(ss, off);
            if (lane == 0) red[w] = ss;
        }
        __syncthreads();

        // ===== P7a: normalize + gate -> matrices (+ bf16 copy) + tb =====
        {
            float ssum = 0.f;
#pragma unroll
            for (int i = 0; i < 16; ++i) ssum += red[i];
            const float inv = __builtin_amdgcn_rsqf(ssum);
            const size_t mbase = ((size_t)b * T_STEPS + t) * 4096;
#pragma unroll
            for (int it = 0; it < 4; ++it) {
                const int e = it * 1024 + tid;
                const int ci = e >> 6, cj = e & 63;
                const float tv = tf[ci * 67 + cj] * inv;
                const float g = fsigm(fabsf(tv) + gate_bias[e]);
                const float val = tv * g;
                matrices[mbase + e] = val;
                const short vb = f2bs(val);
                if (use_mb16) mb16[mbase + e] = vb;
                tb[swz64(ci, cj)] = vb;
            }
        }
        __syncthreads();

        // ===== P7b: h = tb @ h_postGRU (B from hbT) -> h32, hb =====
        {
            const int m = w >> 2, n = w & 3;
            f32x4 ac = {0, 0, 0, 0};
#pragma unroll
            for (int kk = 0; kk < 2; ++kk) {
                const int ra = m * 16 + ln, rbm = n * 16 + ln;
                short8 a  = *(const short8*)&tb [swz64(ra,  kk * 32 + lh * 8)];
                short8 bm = *(const short8*)&hbT[swz64(rbm, kk * 32 + lh * 8)];
                ac = MFMA16(a, bm, ac);
            }
#pragma unroll
            for (int q = 0; q < 4; ++q) {
                const int row = m * 16 + lh * 4 + q;
                const int col = n * 16 + ln;
                h32[row * 67 + col] = ac[q];
                hb[swz64(row, col)] = f2bs(ac[q]);
            }
        }
        __syncthreads();
    }
    // final predictor output not needed for t = T-1 (reference uses t=0..T-2)
}

// ---------------- copy x[:,1:,:] ----------------------------------------------------------
__global__ void copyx_kernel(const float* __restrict__ x, float* __restrict__ out5)
{
    int i = blockIdx.x * 256 + threadIdx.x;
    if (i < B_BATCH * (T_STEPS - 1) * C_COMP) {
        int b = i / ((T_STEPS - 1) * C_COMP);
        int r = i - b * (T_STEPS - 1) * C_COMP;
        out5[i] = x[(size_t)b * (T_STEPS * C_COMP) + r + C_COMP];
    }
}

// ---------------- clf1 fallback: A fp32 (reg-convert) x B bf16 -> bf16 C ------------------
__global__ __launch_bounds__(256) void gemm1_kernel(
    const float* __restrict__ A, const short* __restrict__ Bw,
    const float* __restrict__ bias, short* __restrict__ Cb,
    const int M, const int N, const int K)
{
    __shared__ __align__(16) short Asb[128 * 64];
    __shared__ __align__(16) short Bsb[128 * 64];
    const int tid = threadIdx.x;
    const int w = tid >> 6, lane = tid & 63;
    const int ln = lane & 15, lh = lane >> 4;
    const int wr = w >> 1, wc = w & 1;

    const int ntc = N >> 7;
    const int g = blockIdx.x;
    const int xcd = g & 7, chunk = g >> 3;
    const int mt = xcd * ((M >> 7) >> 3) + chunk / ntc;
    const int nt = chunk % ntc;
    const int m0 = mt << 7, n0 = nt << 7;

    const int ar = tid >> 1;
    const int ac = (tid & 1) << 5;
    const short* bsrc = Bw + (size_t)(n0 + w * 32 + (lane >> 3)) * K + ((lane & 7) << 3);
    short* bdst = &Bsb[w * 32 * 64 + lane * 8];

    f32x4 acc[4][4];
#pragma unroll
    for (int m = 0; m < 4; ++m)
#pragma unroll
        for (int n = 0; n < 4; ++n) acc[m][n] = (f32x4){0, 0, 0, 0};

    for (int k0 = 0; k0 < K; k0 += 64) {
        const float* arow = A + (size_t)(m0 + ar) * K + k0 + ac;
        float4 av[8];
#pragma unroll
        for (int i = 0; i < 8; ++i) av[i] = *reinterpret_cast<const float4*>(arow + i * 4);
        short8 cv[4];
#pragma unroll
        for (int i = 0; i < 4; ++i) {
            cv[i][0] = f2bs(av[2*i].x);   cv[i][1] = f2bs(av[2*i].y);
            cv[i][2] = f2bs(av[2*i].z);   cv[i][3] = f2bs(av[2*i].w);
            cv[i][4] = f2bs(av[2*i+1].x); cv[i][5] = f2bs(av[2*i+1].y);
            cv[i][6] = f2bs(av[2*i+1].z); cv[i][7] = f2bs(av[2*i+1].w);
        }
        __syncthreads();
#pragma unroll
        for (int i = 0; i < 4; ++i)
            *reinterpret_cast<short8*>(&Asb[ar * 64 + ac + i * 8]) = cv[i];
#pragma unroll
        for (int i = 0; i < 4; ++i)
            async16(bdst + i * 512, bsrc + (size_t)i * 8 * K + k0);
        __syncthreads();
#pragma unroll
        for (int kk = 0; kk < 2; ++kk) {
            short8 af[4], bfr[4];
#pragma unroll
            for (int m = 0; m < 4; ++m)
                af[m] = *reinterpret_cast<const short8*>(&Asb[(wr*64 + m*16 + ln)*64 + kk*32 + lh*8]);
#pragma unroll
            for (int n = 0; n < 4; ++n)
                bfr[n] = *reinterpret_cast<const short8*>(&Bsb[(wc*64 + n*16 + ln)*64 + kk*32 + lh*8]);
#pragma unroll
            for (int m = 0; m < 4; ++m)
#pragma unroll
                for (int n = 0; n < 4; ++n)
                    acc[m][n] = MFMA16(af[m], bfr[n], acc[m][n]);
        }
    }
#pragma unroll
    for (int n = 0; n < 4; ++n) {
        const int col = n0 + wc * 64 + n * 16 + ln;
        const float bv = bias[col];
#pragma unroll
        for (int m = 0; m < 4; ++m)
#pragma unroll
            for (int q = 0; q < 4; ++q) {
                const int row = m0 + wr * 64 + m * 16 + lh * 4 + q;
                Cb[(size_t)row * N + col] = f2bs(fmaxf(acc[m][n][q] + bv, 0.f));
            }
    }
}

// ---------------- bf16 x bf16 GEMM via gload_lds (clf1-bf16 / clf2) -----------------------
__global__ __launch_bounds__(256) void gemm2_kernel(
    const short* __restrict__ Ab, const short* __restrict__ Bw,
    const float* __restrict__ bias, short* __restrict__ Cb,
    const int M, const int N, const int K)
{
    __shared__ __align__(16) short Asb[128 * 64];
    __shared__ __align__(16) short Bsb[128 * 64];
    const int tid = threadIdx.x;
    const int w = tid >> 6, lane = tid & 63;
    const int ln = lane & 15, lh = lane >> 4;
    const int wr = w >> 1, wc = w & 1;

    const int ntc = N >> 7;
    const int g = blockIdx.x;
    const int xcd = g & 7, chunk = g >> 3;
    const int mt = xcd * ((M >> 7) >> 3) + chunk / ntc;
    const int nt = chunk % ntc;
    const int m0 = mt << 7, n0 = nt << 7;

    const short* asrc = Ab + (size_t)(m0 + w * 32 + (lane >> 3)) * K + ((lane & 7) << 3);
    const short* bsrc = Bw + (size_t)(n0 + w * 32 + (lane >> 3)) * K + ((lane & 7) << 3);
    short* adst = &Asb[w * 32 * 64 + lane * 8];
    short* bdst = &Bsb[w * 32 * 64 + lane * 8];

    f32x4 acc[4][4];
#pragma unroll
    for (int m = 0; m < 4; ++m)
#pragma unroll
        for (int n = 0; n < 4; ++n) acc[m][n] = (f32x4){0, 0, 0, 0};

    for (int k0 = 0; k0 < K; k0 += 64) {
        __syncthreads();
#pragma unroll
        for (int i = 0; i < 4; ++i) {
            async16(adst + i * 512, asrc + (size_t)i * 8 * K + k0);
            async16(bdst + i * 512, bsrc + (size_t)i * 8 * K + k0);
        }
        __syncthreads();
#pragma unroll
        for (int kk = 0; kk < 2; ++kk) {
            short8 af[4], bfr[4];
#pragma unroll
            for (int m = 0; m < 4; ++m)
                af[m] = *reinterpret_cast<const short8*>(&Asb[(wr*64 + m*16 + ln)*64 + kk*32 + lh*8]);
#pragma unroll
            for (int n = 0; n < 4; ++n)
                bfr[n] = *reinterpret_cast<const short8*>(&Bsb[(wc*64 + n*16 + ln)*64 + kk*32 + lh*8]);
#pragma unroll
            for (int m = 0; m < 4; ++m)
#pragma unroll
                for (int n = 0; n < 4; ++n)
                    acc[m][n] = MFMA16(af[m], bfr[n], acc[m][n]);
        }
    }
#pragma unroll
    for (int n = 0; n < 4; ++n) {
        const int col = n0 + wc * 64 + n * 16 + ln;
        const float bv = bias[col];
#pragma unroll
        for (int m = 0; m < 4; ++m)
#pragma unroll
            for (int q = 0; q < 4; ++q) {
                const int row = m0 + wr * 64 + m * 16 + lh * 4 + q;
                Cb[(size_t)row * N + col] = f2bs(fmaxf(acc[m][n][q] + bv, 0.f));
            }
    }
}

// ---------------- clf3: [M,1024] bf16 -> time_logits [M,2] --------------------------------
__global__ __launch_bounds__(256) void clf3_kernel(const short* __restrict__ h2b,
    const float* __restrict__ w3, const float* __restrict__ b3, float* __restrict__ TL)
{
    const int lane = threadIdx.x & 63;
    const int w = threadIdx.x >> 6;
    const size_t r = (size_t)blockIdx.x * 4 + w;
    const short* hr = h2b + r * 1024;
    float a0 = 0.f, a1 = 0.f;
#pragma unroll
    for (int half = 0; half < 2; ++half) {
        const int k = half * 512 + lane * 8;
        short8 hv = *(const short8*)&hr[k];
#pragma unroll
        for (int u = 0; u < 8; ++u) {
            const float hf = bf2f(hv[u]);
            a0 = fmaf(hf, w3[k + u], a0);
            a1 = fmaf(hf, w3[1024 + k + u], a1);
        }
    }
    for (int off = 32; off; off >>= 1) { a0 += __shfl_xor(a0, off); a1 += __shfl_xor(a1, off); }
    if (lane == 0) {
        TL[r * 2 + 0] = a0 + b3[0];
        TL[r * 2 + 1] = a1 + b3[1];
    }
}

__global__ void logits_kernel(const float* __restrict__ TL, float* __restrict__ out)
{
    const int tid = threadIdx.x;
    if (tid >= 128) return;
    const int b = tid >> 1, o = tid & 1;
    float s = 0.f;
    for (int t = 0; t < T_STEPS; ++t) s += TL[((size_t)b * T_STEPS + t) * 2 + o];
    out[b * 2 + o] = s * (1.0f / 256.0f);
}

extern "C" void kernel_launch(void* const* d_in, const int* in_sizes, int n_in,
                              void* d_out, int out_size, void* d_ws, size_t ws_size,
                              hipStream_t stream)
{
    const float* x       = (const float*)d_in[0];
    const float* embed_w = (const float*)d_in[1];
    const float* embed_b = (const float*)d_in[2];
    const float* w_ih    = (const float*)d_in[3];
    const float* w_hh    = (const float*)d_in[4];
    const float* b_ih    = (const float*)d_in[5];
    const float* b_hh    = (const float*)d_in[6];
    const float* q1w = (const float*)d_in[7],  *q1b = (const float*)d_in[8];
    const float* q2w = (const float*)d_in[9],  *q2b = (const float*)d_in[10];
    const float* q3w = (const float*)d_in[11], *q3b = (const float*)d_in[12];
    const float* k1w = (const float*)d_in[13], *k1b = (const float*)d_in[14];
    const float* k2w = (const float*)d_in[15], *k2b = (const float*)d_in[16];
    const float* k3w = (const float*)d_in[17], *k3b = (const float*)d_in[18];
    const float* gate_bias = (const float*)d_in[19];
    const float* c1w = (const float*)d_in[20], *c1b = (const float*)d_in[21];
    const float* c2w = (const float*)d_in[22], *c2b = (const float*)d_in[23];
    const float* c3w = (const float*)d_in[24], *c3b = (const float*)d_in[25];
    const float* pw  = (const float*)d_in[26], *pb  = (const float*)d_in[27];

    float* out       = (float*)d_out;
    float* logits    = out;
    float* matrices  = out + MAT_OFF;
    float* TL        = out + TL_OFF;
    float* predicted = out + PRED_OFF;
    float* xcopy     = out + XC_OFF;

    float* ws   = (float*)d_ws;
    float* avec = ws;
    float* cvec = ws + 192;
    short* wsw  = (short*)((char*)d_ws + WSW_BYTE_OFF);
    short* c1wb = (short*)((char*)d_ws + C1WB_BYTE);
    short* c2wb = (short*)((char*)d_ws + C2WB_BYTE);
    short* h1b  = (short*)((char*)d_ws + H1B_BYTE);
    short* h2b  = (short*)((char*)d_ws + H2B_BYTE);

    const int use_mb16 = (ws_size >= MB16_BYTE + 134217728ULL) ? 1 : 0;
    short* mb16 = use_mb16 ? (short*)((char*)d_ws + MB16_BYTE) : (short*)d_ws; // unused if 0

    precompute_kernel<<<1, 256, 0, stream>>>(w_ih, embed_w, embed_b, b_ih, avec, cvec);

    tobf16_kernel<<<(12288 + 255) / 256, 256, 0, stream>>>(w_hh, wsw + WHH_OFF, 12288);
    tobf16_kernel<<<(8192  + 255) / 256, 256, 0, stream>>>(q1w,  wsw + Q1_OFF,  8192);
    tobf16_kernel<<<(8192  + 255) / 256, 256, 0, stream>>>(k1w,  wsw + K1_OFF,  8192);
    tobf16_kernel<<<(16384 + 255) / 256, 256, 0, stream>>>(q2w,  wsw + Q2_OFF,  16384);
    tobf16_kernel<<<(16384 + 255) / 256, 256, 0, stream>>>(k2w,  wsw + K2_OFF,  16384);
    tobf16_kernel<<<(16384 + 255) / 256, 256, 0, stream>>>(q3w,  wsw + Q3_OFF,  16384);
    tobf16_kernel<<<(16384 + 255) / 256, 256, 0, stream>>>(k3w,  wsw + K3_OFF,  16384);
    tobf16_kernel<<<(2048 * 4096 + 255) / 256, 256, 0, stream>>>(c1w, c1wb, 2048 * 4096);
    tobf16_kernel<<<(1024 * 2048 + 255) / 256, 256, 0, stream>>>(c2w, c2wb, 1024 * 2048);

    scan_kernel<<<B_BATCH, 1024, 0, stream>>>(x, b_hh, avec, cvec, wsw,
        q1b, q2b, q3b, k1b, k2b, k3b, gate_bias, pw, pb, matrices, predicted,
        mb16, use_mb16);

    copyx_kernel<<<(B_BATCH * (T_STEPS - 1) * C_COMP + 255) / 256, 256, 0, stream>>>(x, xcopy);

    const int Mtot = B_BATCH * T_STEPS;   // 16384
    if (use_mb16) {
        gemm2_kernel<<<(Mtot / 128) * (2048 / 128), 256, 0, stream>>>(
            mb16, c1wb, c1b, h1b, Mtot, 2048, 4096);
    } else {
        gemm1_kernel<<<(Mtot / 128) * (2048 / 128), 256, 0, stream>>>(
            matrices, c1wb, c1b, h1b, Mtot, 2048, 4096);
    }
    gemm2_kernel<<<(Mtot / 128) * (1024 / 128), 256, 0, stream>>>(
        h1b, c2wb, c2b, h2b, Mtot, 1024, 2048);
    clf3_kernel<<<Mtot / 4, 256, 0, stream>>>(h2b, c3w, c3b, TL);
    logits_kernel<<<1, 128, 0, stream>>>(TL, logits);
}

// Round 5
// 3250.189 us; speedup vs baseline: 1.0870x; 1.0870x over previous
//
#include <hip/hip_runtime.h>
#include <hip/hip_bf16.h>
#include <math.h>

#define B_BATCH 64
#define T_STEPS 256
#define C_COMP  64

// ws layout: floats [0..191] avec, [192..383] cvec; byte 2048+ : scan bf16 weights
#define WSW_BYTE_OFF 2048
#define WHH_OFF 0
#define Q1_OFF 12288
#define K1_OFF 20480
#define Q2_OFF 28672
#define K2_OFF 45056
#define Q3_OFF 61440
#define K3_OFF 77824
// classifier scratch (bytes)
#define C1WB_BYTE 262144
#define C2WB_BYTE 17039360
#define H1B_BYTE  21233664
#define H2B_BYTE  88342528
#define MB16_BYTE 121896960ULL

// output offsets (floats)
#define MAT_OFF  128
#define TL_OFF   67108992
#define PRED_OFF 67141760
#define XC_OFF   68186240

typedef __attribute__((ext_vector_type(8))) short short8;
typedef __attribute__((ext_vector_type(4))) float f32x4;
#define MFMA16(a,b,c) __builtin_amdgcn_mfma_f32_16x16x32_bf16(a,b,c,0,0,0)

__device__ __forceinline__ float fsigm(float v) {
    return __builtin_amdgcn_rcpf(1.0f + __expf(-v));
}
__device__ __forceinline__ float ftanh(float v) {
    return 1.0f - 2.0f * __builtin_amdgcn_rcpf(__expf(2.0f * v) + 1.0f);
}
__device__ __forceinline__ short f2bs(float f) {  // RNE f32->bf16 bits
    unsigned u = __float_as_uint(f);
    u += 0x7fffu + ((u >> 16) & 1u);
    return (short)(u >> 16);
}
__device__ __forceinline__ float bf2f(short s) {
    return __uint_as_float(((unsigned)(unsigned short)s) << 16);
}
// LDS-only barrier: waits DS ops, does NOT drain vmcnt (global stores keep flowing).
// Safe here: all in-loop global stores have no in-kernel consumer; x-load is
// consumed via register dataflow (compiler inserts its own vmcnt for that).
__device__ __forceinline__ void bar_lds() {
    asm volatile("s_waitcnt lgkmcnt(0)" ::: "memory");
    __builtin_amdgcn_s_barrier();
}
// XOR swizzle for bf16 tiles (bank-spread across rows)
__device__ __forceinline__ int swz64(int row, int col) {
    return row * 64 + (col ^ (((row >> 1) & 7) << 3));
}
__device__ __forceinline__ int swz128(int row, int col) {
    return row * 128 + (col ^ (((row >> 1) & 7) << 3));
}
__device__ __forceinline__ void async16(void* lds, const void* g) {
    __builtin_amdgcn_global_load_lds((const __attribute__((address_space(1))) void*)g,
                                     (__attribute__((address_space(3))) void*)lds, 16, 0, 0);
}

// ---------------- precompute rank-1 embedding+input path --------------------------------
__global__ void precompute_kernel(const float* __restrict__ w_ih,
                                  const float* __restrict__ embed_w,
                                  const float* __restrict__ embed_b,
                                  const float* __restrict__ b_ih,
                                  float* __restrict__ avec, float* __restrict__ cvec)
{
    int g = threadIdx.x;
    if (g < 192) {
        float a = 0.f, c = 0.f;
        for (int e = 0; e < 32; ++e) {
            float w = w_ih[g * 32 + e];
            a += w * embed_w[e];
            c += w * embed_b[e];
        }
        avec[g] = a;
        cvec[g] = c + b_ih[g];
    }
}

__global__ void tobf16_kernel(const float* __restrict__ src, short* __restrict__ dst, int n)
{
    int i = blockIdx.x * 256 + threadIdx.x;
    if (i < n) dst[i] = f2bs(src[i]);
}

// expand bf16 matrices -> fp32 output (memory-bound, full grid)
__global__ void expand_kernel(const short* __restrict__ mb, float* __restrict__ mat)
{
    const size_t i = ((size_t)blockIdx.x * 256 + threadIdx.x) * 8;
    short8 v = *(const short8*)&mb[i];
    float4 lo, hi;
    lo.x = bf2f(v[0]); lo.y = bf2f(v[1]); lo.z = bf2f(v[2]); lo.w = bf2f(v[3]);
    hi.x = bf2f(v[4]); hi.y = bf2f(v[5]); hi.z = bf2f(v[6]); hi.w = bf2f(v[7]);
    *reinterpret_cast<float4*>(&mat[i])     = lo;
    *reinterpret_cast<float4*>(&mat[i + 4]) = hi;
}

// one MLP layer, two 16-col strips per wave
template<int KST, int AST, bool RELU>
__device__ __forceinline__ void two_strip(
    const short* __restrict__ A,
    const short8* __restrict__ B0, const short8* __restrict__ B1,
    const float bias0, const float bias1,
    short* __restrict__ outb, const int s0, const int s1, const int ln, const int lh)
{
    f32x4 acc0[4], acc1[4];
#pragma unroll
    for (int m = 0; m < 4; ++m) {
        acc0[m] = (f32x4){bias0, bias0, bias0, bias0};
        acc1[m] = (f32x4){bias1, bias1, bias1, bias1};
    }
#pragma unroll
    for (int kk = 0; kk < KST; ++kk)
#pragma unroll
        for (int m = 0; m < 4; ++m) {
            const int row = m * 16 + ln;
            short8 a = *(const short8*)&A[row * AST + ((kk * 32 + lh * 8) ^ (((row >> 1) & 7) << 3))];
            acc0[m] = MFMA16(a, B0[kk], acc0[m]);
            acc1[m] = MFMA16(a, B1[kk], acc1[m]);
        }
#pragma unroll
    for (int m = 0; m < 4; ++m)
#pragma unroll
        for (int q = 0; q < 4; ++q) {
            const int row = m * 16 + lh * 4 + q;
            float v0 = acc0[m][q], v1 = acc1[m][q];
            if (RELU) { v0 = fmaxf(v0, 0.f); v1 = fmaxf(v1, 0.f); }
            outb[swz128(row, s0 * 16 + ln)] = f2bs(v0);
            outb[swz128(row, s1 * 16 + ln)] = f2bs(v1);
        }
}

// ---------------- the scan: one block (8 waves) per batch -------------------------------
__global__ __launch_bounds__(512) void scan_kernel(
    const float* __restrict__ x, const float* __restrict__ b_hh,
    const float* __restrict__ avec, const float* __restrict__ cvec,
    const short* __restrict__ wsw,
    const float* __restrict__ q1b, const float* __restrict__ q2b, const float* __restrict__ q3b,
    const float* __restrict__ k1b, const float* __restrict__ k2b, const float* __restrict__ k3b,
    const float* __restrict__ gate_bias,
    const float* __restrict__ pred_w, const float* __restrict__ pred_b,
    float* __restrict__ matrices, float* __restrict__ predicted,
    short* __restrict__ mb16, const int use_mb16)
{
    __shared__ __align__(16) float h32[64 * 65];
    __shared__ __align__(16) short hb [64 * 64];
    __shared__ __align__(16) short hbT[64 * 64];
    __shared__ __align__(16) short qf [64 * 128];
    __shared__ __align__(16) short kf [64 * 128];
    __shared__ __align__(16) float gbias_s[64 * 65];
    __shared__ __align__(16) char arena[65536];
    __shared__ float avec_s[192], cvec_s[192], bhh_s[192], pw_s[64], xrow[64], red[8];

    float* gates = (float*)arena;                // [64][193] f32 (P1->P2)
    short* act1q = (short*)arena;                // [64][128] swz (L1->L2)
    short* act1k = (short*)(arena + 16384);
    short* act2q = (short*)(arena + 32768);      // (L2->L3)
    short* act2k = (short*)(arena + 49152);
    float* tf    = (float*)arena;                // [64][65] f32 (P6->P7)

    const int tid = threadIdx.x;
    const int b = blockIdx.x;
    const int w = tid >> 6, lane = tid & 63;
    const int ln = lane & 15, lh = lane >> 4;
    const int path = w >> 2;                     // 0 = q, 1 = k
    const int wq = w & 3;

    for (int i = tid; i < 64 * 65; i += 512) h32[i] = 0.f;
    for (int i = tid; i < 64 * 64; i += 512) { hb[i] = 0; hbT[i] = 0; }
    for (int i = tid; i < 4096; i += 512)
        gbias_s[(i >> 6) * 65 + (i & 63)] = gate_bias[i];
    if (tid < 192) { avec_s[tid] = avec[tid]; cvec_s[tid] = cvec[tid]; bhh_s[tid] = b_hh[tid]; }
    if (tid < 64) pw_s[tid] = pred_w[tid];
    const float pbv = pred_b[0];

    // ---- preload weight B-fragments (constant across all t) ----
    const short* whh_b = wsw + WHH_OFF;
    const short* l1w = path ? wsw + K1_OFF : wsw + Q1_OFF;
    const short* l2w = path ? wsw + K2_OFF : wsw + Q2_OFF;
    const short* l3w = path ? wsw + K3_OFF : wsw + Q3_OFF;
    const float* l1b = path ? k1b : q1b;
    const float* l2b = path ? k2b : q2b;
    const float* l3b = path ? k3b : q3b;

    short8 Bg[2][2], B1[2][2], B2[2][4], B3[2][4];
    {
        const int sg1 = (w < 4) ? (w + 8) : w;
#pragma unroll
        for (int kk = 0; kk < 2; ++kk) {
            Bg[0][kk] = *(const short8*)&whh_b[(w   * 16 + ln) * 64 + kk * 32 + lh * 8];
            Bg[1][kk] = *(const short8*)&whh_b[(sg1 * 16 + ln) * 64 + kk * 32 + lh * 8];
        }
#pragma unroll
        for (int s = 0; s < 2; ++s) {
            const int strip = wq + s * 4;
#pragma unroll
            for (int kk = 0; kk < 2; ++kk)
                B1[s][kk] = *(const short8*)&l1w[(strip * 16 + ln) * 64 + kk * 32 + lh * 8];
#pragma unroll
            for (int kk = 0; kk < 4; ++kk) {
                B2[s][kk] = *(const short8*)&l2w[(strip * 16 + ln) * 128 + kk * 32 + lh * 8];
                B3[s][kk] = *(const short8*)&l3w[(strip * 16 + ln) * 128 + kk * 32 + lh * 8];
            }
        }
    }
    const float b1v0 = l1b[wq * 16 + ln],     b1v1 = l1b[(wq + 4) * 16 + ln];
    const float b2v0 = l2b[wq * 16 + ln],     b2v1 = l2b[(wq + 4) * 16 + ln];
    const float b3v0 = l3b[wq * 16 + ln],     b3v1 = l3b[(wq + 4) * 16 + ln];
    __syncthreads();

    for (int t = 0; t < T_STEPS; ++t) {
        // ===== P1: x prefetch, predictor(t-1), gates = hb @ w_hh^T =====
        float xpre = 0.f;
        if (tid < 64) xpre = x[((size_t)b * T_STEPS + t) * 64 + tid];
        if (t > 0) {
            const int c = tid >> 3, jj = tid & 7;
            float p = 0.f;
#pragma unroll
            for (int u = 0; u < 8; ++u) p = fmaf(h32[c * 65 + jj * 8 + u], pw_s[jj * 8 + u], p);
            p += __shfl_xor(p, 1); p += __shfl_xor(p, 2); p += __shfl_xor(p, 4);
            if (jj == 0) predicted[((size_t)b * (T_STEPS - 1) + (t - 1)) * 64 + c] = p + pbv;
        }
        {
            f32x4 a0[4], a1[4];
#pragma unroll
            for (int m = 0; m < 4; ++m) { a0[m] = (f32x4){0,0,0,0}; a1[m] = (f32x4){0,0,0,0}; }
#pragma unroll
            for (int kk = 0; kk < 2; ++kk)
#pragma unroll
                for (int m = 0; m < 4; ++m) {
                    short8 av = *(const short8*)&hb[swz64(m * 16 + ln, kk * 32 + lh * 8)];
                    a0[m] = MFMA16(av, Bg[0][kk], a0[m]);
                    a1[m] = MFMA16(av, Bg[1][kk], a1[m]);
                }
#pragma unroll
            for (int m = 0; m < 4; ++m)
#pragma unroll
                for (int q = 0; q < 4; ++q)
                    gates[(m * 16 + lh * 4 + q) * 193 + w * 16 + ln] = a0[m][q];
            if (w < 4) {
#pragma unroll
                for (int m = 0; m < 4; ++m)
#pragma unroll
                    for (int q = 0; q < 4; ++q)
                        gates[(m * 16 + lh * 4 + q) * 193 + (w + 8) * 16 + ln] = a1[m][q];
            }
        }
        if (tid < 64) xrow[tid] = xpre;
        bar_lds();

        // ===== P2: GRU elementwise -> h32, hb, hbT =====
        {
            const int c = tid >> 3, j0 = (tid & 7) * 8;
            const float xv = xrow[c];
            short8 hv8;
#pragma unroll
            for (int jj = 0; jj < 8; ++jj) {
                const int j = j0 + jj;
                const float ghr = gates[c * 193 + j]       + bhh_s[j];
                const float ghz = gates[c * 193 + 64 + j]  + bhh_s[64 + j];
                const float ghn = gates[c * 193 + 128 + j] + bhh_s[128 + j];
                const float r = fsigm(fmaf(xv, avec_s[j],        cvec_s[j])        + ghr);
                const float z = fsigm(fmaf(xv, avec_s[64 + j],   cvec_s[64 + j])   + ghz);
                const float n = ftanh(fmaf(xv, avec_s[128 + j], cvec_s[128 + j]) + r * ghn);
                const float hold = h32[c * 65 + j];
                const float hn = fmaf(z, hold - n, n);
                h32[c * 65 + j] = hn;
                const short hv = f2bs(hn);
                hv8[jj] = hv;
                hbT[swz64(j, c)] = hv;
            }
            *(short8*)&hb[c * 64 + (j0 ^ (((c >> 1) & 7) << 3))] = hv8;
        }
        bar_lds();

        // ===== L1-L3: q / k MLPs (waves 0-3 q, 4-7 k; two strips each) =====
        two_strip<2, 64,  true >(hb, B1[0], B1[1], b1v0, b1v1,
                                 path ? act1k : act1q, wq, wq + 4, ln, lh);
        bar_lds();
        two_strip<4, 128, true >(path ? act1k : act1q, B2[0], B2[1], b2v0, b2v1,
                                 path ? act2k : act2q, wq, wq + 4, ln, lh);
        bar_lds();
        two_strip<4, 128, false>(path ? act2k : act2q, B3[0], B3[1], b3v0, b3v1,
                                 path ? kf : qf, wq, wq + 4, ln, lh);
        bar_lds();

        // ===== P6: transfer = qf @ kf^T -> tf f32, sumsq -> red =====
        {
            const int m = wq, n0 = w >> 2;
            f32x4 ac0 = {0,0,0,0}, ac1 = {0,0,0,0};
#pragma unroll
            for (int kk = 0; kk < 4; ++kk) {
                short8 a  = *(const short8*)&qf[swz128(m * 16 + ln, kk * 32 + lh * 8)];
                short8 b0 = *(const short8*)&kf[swz128(n0 * 16 + ln, kk * 32 + lh * 8)];
                short8 b1 = *(const short8*)&kf[swz128((n0 + 2) * 16 + ln, kk * 32 + lh * 8)];
                ac0 = MFMA16(a, b0, ac0);
                ac1 = MFMA16(a, b1, ac1);
            }
            float ss = 0.f;
#pragma unroll
            for (int q = 0; q < 4; ++q) {
                const int row = m * 16 + lh * 4 + q;
                tf[row * 65 + n0 * 16 + ln]       = ac0[q];
                tf[row * 65 + (n0 + 2) * 16 + ln] = ac1[q];
                ss = fmaf(ac0[q], ac0[q], fmaf(ac1[q], ac1[q], ss));
            }
#pragma unroll
            for (int off = 1; off < 64; off <<= 1) ss += __shfl_xor(ss, off);
            if (lane == 0) red[w] = ss;
        }
        bar_lds();

        // ===== P7: norm+gate (A-frags in regs, global store) then h = T @ h_post =====
        {
            const int m = wq, n0 = w >> 2;   // waves n0=0,1 duplicate gate math for rows m*16+ln
            const float ssum = red[0]+red[1]+red[2]+red[3]+red[4]+red[5]+red[6]+red[7];
            const float inv = __builtin_amdgcn_rsqf(ssum);
            const int row = m * 16 + ln;
            short8 af[2];
            float vals[16];
#pragma unroll
            for (int kk = 0; kk < 2; ++kk)
#pragma unroll
                for (int u = 0; u < 8; ++u) {
                    const int col = kk * 32 + lh * 8 + u;
                    const float tv = tf[row * 65 + col] * inv;
                    const float g = fsigm(fabsf(tv) + gbias_s[row * 65 + col]);
                    const float v = tv * g;
                    vals[kk * 8 + u] = v;
                    af[kk][u] = f2bs(v);
                }
            const size_t mbase = ((size_t)b * T_STEPS + t) * 4096;
            if (w < 4) {     // n0==0 waves own the global store
                if (use_mb16) {
#pragma unroll
                    for (int kk = 0; kk < 2; ++kk)
                        *(short8*)&mb16[mbase + row * 64 + kk * 32 + lh * 8] = af[kk];
                } else {
#pragma unroll
                    for (int kk = 0; kk < 2; ++kk) {
                        float4 lo = {vals[kk*8+0], vals[kk*8+1], vals[kk*8+2], vals[kk*8+3]};
                        float4 hi = {vals[kk*8+4], vals[kk*8+5], vals[kk*8+6], vals[kk*8+7]};
                        *reinterpret_cast<float4*>(&matrices[mbase + row * 64 + kk * 32 + lh * 8])     = lo;
                        *reinterpret_cast<float4*>(&matrices[mbase + row * 64 + kk * 32 + lh * 8 + 4]) = hi;
                    }
                }
            }
            // P7b: hnew = T @ h_post, B-frags from hbT
            f32x4 hc0 = {0,0,0,0}, hc1 = {0,0,0,0};
#pragma unroll
            for (int kk = 0; kk < 2; ++kk) {
                short8 b0 = *(const short8*)&hbT[swz64(n0 * 16 + ln, kk * 32 + lh * 8)];
                short8 b1 = *(const short8*)&hbT[swz64((n0 + 2) * 16 + ln, kk * 32 + lh * 8)];
                hc0 = MFMA16(af[kk], b0, hc0);
                hc1 = MFMA16(af[kk], b1, hc1);
            }
#pragma unroll
            for (int q = 0; q < 4; ++q) {
                const int orow = m * 16 + lh * 4 + q;
                const int c0 = n0 * 16 + ln, c1 = (n0 + 2) * 16 + ln;
                h32[orow * 65 + c0] = hc0[q];
                h32[orow * 65 + c1] = hc1[q];
                hb[swz64(orow, c0)] = f2bs(hc0[q]);
                hb[swz64(orow, c1)] = f2bs(hc1[q]);
            }
        }
        bar_lds();
    }
}

// ---------------- copy x[:,1:,:] ----------------------------------------------------------
__global__ void copyx_kernel(const float* __restrict__ x, float* __restrict__ out5)
{
    int i = blockIdx.x * 256 + threadIdx.x;
    if (i < B_BATCH * (T_STEPS - 1) * C_COMP) {
        int b = i / ((T_STEPS - 1) * C_COMP);
        int r = i - b * (T_STEPS - 1) * C_COMP;
        out5[i] = x[(size_t)b * (T_STEPS * C_COMP) + r + C_COMP];
    }
}

// ---------------- clf1 fallback: A fp32 (reg-convert) x B bf16 -> bf16 C ------------------
__global__ __launch_bounds__(256) void gemm1_kernel(
    const float* __restrict__ A, const short* __restrict__ Bw,
    const float* __restrict__ bias, short* __restrict__ Cb,
    const int M, const int N, const int K)
{
    __shared__ __align__(16) short Asb[128 * 64];
    __shared__ __align__(16) short Bsb[128 * 64];
    const int tid = threadIdx.x;
    const int w = tid >> 6, lane = tid & 63;
    const int ln = lane & 15, lh = lane >> 4;
    const int wr = w >> 1, wc = w & 1;

    const int ntc = N >> 7;
    const int g = blockIdx.x;
    const int xcd = g & 7, chunk = g >> 3;
    const int mt = xcd * ((M >> 7) >> 3) + chunk / ntc;
    const int nt = chunk % ntc;
    const int m0 = mt << 7, n0 = nt << 7;

    const int ar = tid >> 1;
    const int ac = (tid & 1) << 5;
    const short* bsrc = Bw + (size_t)(n0 + w * 32 + (lane >> 3)) * K + ((lane & 7) << 3);
    short* bdst = &Bsb[w * 32 * 64 + lane * 8];

    f32x4 acc[4][4];
#pragma unroll
    for (int m = 0; m < 4; ++m)
#pragma unroll
        for (int n = 0; n < 4; ++n) acc[m][n] = (f32x4){0, 0, 0, 0};

    for (int k0 = 0; k0 < K; k0 += 64) {
        const float* arow = A + (size_t)(m0 + ar) * K + k0 + ac;
        float4 av[8];
#pragma unroll
        for (int i = 0; i < 8; ++i) av[i] = *reinterpret_cast<const float4*>(arow + i * 4);
        short8 cv[4];
#pragma unroll
        for (int i = 0; i < 4; ++i) {
            cv[i][0] = f2bs(av[2*i].x);   cv[i][1] = f2bs(av[2*i].y);
            cv[i][2] = f2bs(av[2*i].z);   cv[i][3] = f2bs(av[2*i].w);
            cv[i][4] = f2bs(av[2*i+1].x); cv[i][5] = f2bs(av[2*i+1].y);
            cv[i][6] = f2bs(av[2*i+1].z); cv[i][7] = f2bs(av[2*i+1].w);
        }
        __syncthreads();
#pragma unroll
        for (int i = 0; i < 4; ++i)
            *reinterpret_cast<short8*>(&Asb[ar * 64 + ac + i * 8]) = cv[i];
#pragma unroll
        for (int i = 0; i < 4; ++i)
            async16(bdst + i * 512, bsrc + (size_t)i * 8 * K + k0);
        __syncthreads();
#pragma unroll
        for (int kk = 0; kk < 2; ++kk) {
            short8 af[4], bfr[4];
#pragma unroll
            for (int m = 0; m < 4; ++m)
                af[m] = *reinterpret_cast<const short8*>(&Asb[(wr*64 + m*16 + ln)*64 + kk*32 + lh*8]);
#pragma unroll
            for (int n = 0; n < 4; ++n)
                bfr[n] = *reinterpret_cast<const short8*>(&Bsb[(wc*64 + n*16 + ln)*64 + kk*32 + lh*8]);
#pragma unroll
            for (int m = 0; m < 4; ++m)
#pragma unroll
                for (int n = 0; n < 4; ++n)
                    acc[m][n] = MFMA16(af[m], bfr[n], acc[m][n]);
        }
    }
#pragma unroll
    for (int n = 0; n < 4; ++n) {
        const int col = n0 + wc * 64 + n * 16 + ln;
        const float bv = bias[col];
#pragma unroll
        for (int m = 0; m < 4; ++m)
#pragma unroll
            for (int q = 0; q < 4; ++q) {
                const int row = m0 + wr * 64 + m * 16 + lh * 4 + q;
                Cb[(size_t)row * N + col] = f2bs(fmaxf(acc[m][n][q] + bv, 0.f));
            }
    }
}

// ---------------- bf16 x bf16 GEMM via gload_lds (clf1 / clf2) ----------------------------
__global__ __launch_bounds__(256) void gemm2_kernel(
    const short* __restrict__ Ab, const short* __restrict__ Bw,
    const float* __restrict__ bias, short* __restrict__ Cb,
    const int M, const int N, const int K)
{
    __shared__ __align__(16) short Asb[128 * 64];
    __shared__ __align__(16) short Bsb[128 * 64];
    const int tid = threadIdx.x;
    const int w = tid >> 6, lane = tid & 63;
    const int ln = lane & 15, lh = lane >> 4;
    const int wr = w >> 1, wc = w & 1;

    const int ntc = N >> 7;
    const int g = blockIdx.x;
    const int xcd = g & 7, chunk = g >> 3;
    const int mt = xcd * ((M >> 7) >> 3) + chunk / ntc;
    const int nt = chunk % ntc;
    const int m0 = mt << 7, n0 = nt << 7;

    const short* asrc = Ab + (size_t)(m0 + w * 32 + (lane >> 3)) * K + ((lane & 7) << 3);
    const short* bsrc = Bw + (size_t)(n0 + w * 32 + (lane >> 3)) * K + ((lane & 7) << 3);
    short* adst = &Asb[w * 32 * 64 + lane * 8];
    short* bdst = &Bsb[w * 32 * 64 + lane * 8];

    f32x4 acc[4][4];
#pragma unroll
    for (int m = 0; m < 4; ++m)
#pragma unroll
        for (int n = 0; n < 4; ++n) acc[m][n] = (f32x4){0, 0, 0, 0};

    for (int k0 = 0; k0 < K; k0 += 64) {
        __syncthreads();
#pragma unroll
        for (int i = 0; i < 4; ++i) {
            async16(adst + i * 512, asrc + (size_t)i * 8 * K + k0);
            async16(bdst + i * 512, bsrc + (size_t)i * 8 * K + k0);
        }
        __syncthreads();
#pragma unroll
        for (int kk = 0; kk < 2; ++kk) {
            short8 af[4], bfr[4];
#pragma unroll
            for (int m = 0; m < 4; ++m)
                af[m] = *reinterpret_cast<const short8*>(&Asb[(wr*64 + m*16 + ln)*64 + kk*32 + lh*8]);
#pragma unroll
            for (int n = 0; n < 4; ++n)
                bfr[n] = *reinterpret_cast<const short8*>(&Bsb[(wc*64 + n*16 + ln)*64 + kk*32 + lh*8]);
#pragma unroll
            for (int m = 0; m < 4; ++m)
#pragma unroll
                for (int n = 0; n < 4; ++n)
                    acc[m][n] = MFMA16(af[m], bfr[n], acc[m][n]);
        }
    }
#pragma unroll
    for (int n = 0; n < 4; ++n) {
        const int col = n0 + wc * 64 + n * 16 + ln;
        const float bv = bias[col];
#pragma unroll
        for (int m = 0; m < 4; ++m)
#pragma unroll
            for (int q = 0; q < 4; ++q) {
                const int row = m0 + wr * 64 + m * 16 + lh * 4 + q;
                Cb[(size_t)row * N + col] = f2bs(fmaxf(acc[m][n][q] + bv, 0.f));
            }
    }
}

// ---------------- clf3: [M,1024] bf16 -> time_logits [M,2] --------------------------------
__global__ __launch_bounds__(256) void clf3_kernel(const short* __restrict__ h2b,
    const float* __restrict__ w3, const float* __restrict__ b3, float* __restrict__ TL)
{
    const int lane = threadIdx.x & 63;
    const int w = threadIdx.x >> 6;
    const size_t r = (size_t)blockIdx.x * 4 + w;
    const short* hr = h2b + r * 1024;
    float a0 = 0.f, a1 = 0.f;
#pragma unroll
    for (int half = 0; half < 2; ++half) {
        const int k = half * 512 + lane * 8;
        short8 hv = *(const short8*)&hr[k];
#pragma unroll
        for (int u = 0; u < 8; ++u) {
            const float hf = bf2f(hv[u]);
            a0 = fmaf(hf, w3[k + u], a0);
            a1 = fmaf(hf, w3[1024 + k + u], a1);
        }
    }
    for (int off = 32; off; off >>= 1) { a0 += __shfl_xor(a0, off); a1 += __shfl_xor(a1, off); }
    if (lane == 0) {
        TL[r * 2 + 0] = a0 + b3[0];
        TL[r * 2 + 1] = a1 + b3[1];
    }
}

__global__ void logits_kernel(const float* __restrict__ TL, float* __restrict__ out)
{
    const int tid = threadIdx.x;
    if (tid >= 128) return;
    const int b = tid >> 1, o = tid & 1;
    float s = 0.f;
    for (int t = 0; t < T_STEPS; ++t) s += TL[((size_t)b * T_STEPS + t) * 2 + o];
    out[b * 2 + o] = s * (1.0f / 256.0f);
}

extern "C" void kernel_launch(void* const* d_in, const int* in_sizes, int n_in,
                              void* d_out, int out_size, void* d_ws, size_t ws_size,
                              hipStream_t stream)
{
    const float* x       = (const float*)d_in[0];
    const float* embed_w = (const float*)d_in[1];
    const float* embed_b = (const float*)d_in[2];
    const float* w_ih    = (const float*)d_in[3];
    const float* w_hh    = (const float*)d_in[4];
    const float* b_ih    = (const float*)d_in[5];
    const float* b_hh    = (const float*)d_in[6];
    const float* q1w = (const float*)d_in[7],  *q1b = (const float*)d_in[8];
    const float* q2w = (const float*)d_in[9],  *q2b = (const float*)d_in[10];
    const float* q3w = (const float*)d_in[11], *q3b = (const float*)d_in[12];
    const float* k1w = (const float*)d_in[13], *k1b = (const float*)d_in[14];
    const float* k2w = (const float*)d_in[15], *k2b = (const float*)d_in[16];
    const float* k3w = (const float*)d_in[17], *k3b = (const float*)d_in[18];
    const float* gate_bias = (const float*)d_in[19];
    const float* c1w = (const float*)d_in[20], *c1b = (const float*)d_in[21];
    const float* c2w = (const float*)d_in[22], *c2b = (const float*)d_in[23];
    const float* c3w = (const float*)d_in[24], *c3b = (const float*)d_in[25];
    const float* pw  = (const float*)d_in[26], *pb  = (const float*)d_in[27];

    float* out       = (float*)d_out;
    float* logits    = out;
    float* matrices  = out + MAT_OFF;
    float* TL        = out + TL_OFF;
    float* predicted = out + PRED_OFF;
    float* xcopy     = out + XC_OFF;

    float* ws   = (float*)d_ws;
    float* avec = ws;
    float* cvec = ws + 192;
    short* wsw  = (short*)((char*)d_ws + WSW_BYTE_OFF);
    short* c1wb = (short*)((char*)d_ws + C1WB_BYTE);
    short* c2wb = (short*)((char*)d_ws + C2WB_BYTE);
    short* h1b  = (short*)((char*)d_ws + H1B_BYTE);
    short* h2b  = (short*)((char*)d_ws + H2B_BYTE);

    const int use_mb16 = (ws_size >= MB16_BYTE + 134217728ULL) ? 1 : 0;
    short* mb16 = use_mb16 ? (short*)((char*)d_ws + MB16_BYTE) : (short*)d_ws;

    precompute_kernel<<<1, 256, 0, stream>>>(w_ih, embed_w, embed_b, b_ih, avec, cvec);

    tobf16_kernel<<<(12288 + 255) / 256, 256, 0, stream>>>(w_hh, wsw + WHH_OFF, 12288);
    tobf16_kernel<<<(8192  + 255) / 256, 256, 0, stream>>>(q1w,  wsw + Q1_OFF,  8192);
    tobf16_kernel<<<(8192  + 255) / 256, 256, 0, stream>>>(k1w,  wsw + K1_OFF,  8192);
    tobf16_kernel<<<(16384 + 255) / 256, 256, 0, stream>>>(q2w,  wsw + Q2_OFF,  16384);
    tobf16_kernel<<<(16384 + 255) / 256, 256, 0, stream>>>(k2w,  wsw + K2_OFF,  16384);
    tobf16_kernel<<<(16384 + 255) / 256, 256, 0, stream>>>(q3w,  wsw + Q3_OFF,  16384);
    tobf16_kernel<<<(16384 + 255) / 256, 256, 0, stream>>>(k3w,  wsw + K3_OFF,  16384);
    tobf16_kernel<<<(2048 * 4096 + 255) / 256, 256, 0, stream>>>(c1w, c1wb, 2048 * 4096);
    tobf16_kernel<<<(1024 * 2048 + 255) / 256, 256, 0, stream>>>(c2w, c2wb, 1024 * 2048);

    scan_kernel<<<B_BATCH, 512, 0, stream>>>(x, b_hh, avec, cvec, wsw,
        q1b, q2b, q3b, k1b, k2b, k3b, gate_bias, pw, pb, matrices, predicted,
        mb16, use_mb16);

    if (use_mb16)
        expand_kernel<<<32768, 256, 0, stream>>>(mb16, matrices);

    copyx_kernel<<<(B_BATCH * (T_STEPS - 1) * C_COMP + 255) / 256, 256, 0, stream>>>(x, xcopy);

    const int Mtot = B_BATCH * T_STEPS;   // 16384
    if (use_mb16) {
        gemm2_kernel<<<(Mtot / 128) * (2048 / 128), 256, 0, stream>>>(
            mb16, c1wb, c1b, h1b, Mtot, 2048, 4096);
    } else {
        gemm1_kernel<<<(Mtot / 128) * (2048 / 128), 256, 0, stream>>>(
            matrices, c1wb, c1b, h1b, Mtot, 2048, 4096);
    }
    gemm2_kernel<<<(Mtot / 128) * (1024 / 128), 256, 0, stream>>>(
        h1b, c2wb, c2b, h2b, Mtot, 1024, 2048);
    clf3_kernel<<<Mtot / 4, 256, 0, stream>>>(h2b, c3w, c3b, TL);
    logits_kernel<<<1, 128, 0, stream>>>(TL, logits);
}